// Round 5
// baseline (386.681 us; speedup 1.0000x reference)
//
#include <hip/hip_runtime.h>

typedef unsigned short u16;
typedef unsigned int u32;
typedef unsigned long long u64;
typedef __attribute__((ext_vector_type(8))) short bf16x8;
typedef __attribute__((ext_vector_type(4))) float f32x4;

__device__ __forceinline__ u16 f2bf(float f) {  // RNE
  union { float f; u32 u; } v; v.f = f;
  u32 r = v.u + 0x7fffu + ((v.u >> 16) & 1u);
  return (u16)(r >> 16);
}
// pack two positive floats to bf16x2 (bias rounding)
__device__ __forceinline__ u32 pack2bf(float a, float b) {
  union { float f; u32 u; } x, y; x.f = a; y.f = b;
  return ((y.u + 0x8000u) & 0xffff0000u) | ((x.u + 0x8000u) >> 16);
}

// async global->LDS, 16B per lane, wave-uniform LDS base + lane*16
__device__ __forceinline__ void gll16(const u16* g, u16* l) {
  __builtin_amdgcn_global_load_lds((__attribute__((address_space(1))) void*)(void*)g,
                                   (__attribute__((address_space(3))) void*)(void*)l,
                                   16, 0, 0);
}

#define SCALE_C 0.18033688011112042f  // (1/sqrt(64)) * log2(e), folded into Q proj

// ---------------- fp32 -> bf16 convert (vectorized) ----------------
__global__ void conv_bf16(const float* __restrict__ in, u16* __restrict__ out, int n) {
  int i = (blockIdx.x * 256 + threadIdx.x) * 4;
  if (i < n) {
    float4 v = *(const float4*)(in + i);
    ushort4 o;
    o.x = f2bf(v.x); o.y = f2bf(v.y); o.z = f2bf(v.z); o.w = f2bf(v.w);
    *(ushort4*)(out + i) = o;
  }
}

// ------ W[K,N] fp32 -> T[N,K] bf16, LDS-tiled: coalesced read AND write ------
__global__ void transpose_bf16(const float* __restrict__ W, u16* __restrict__ T,
                               int K, int N) {
  __shared__ u16 tile[64 * 72];
  const int k0 = blockIdx.x * 64, n0 = blockIdx.y * 64;
  const int t = threadIdx.x, c = t & 63, rb = t >> 6;
#pragma unroll
  for (int rr = 0; rr < 64; rr += 4) {
    int r = rr + rb;
    tile[r * 72 + c] = f2bf(W[(size_t)(k0 + r) * N + n0 + c]);
  }
  __syncthreads();
#pragma unroll
  for (int rr = 0; rr < 64; rr += 4) {
    int n = rr + rb;
    T[(size_t)(n0 + n) * K + k0 + c] = tile[c * 72 + n];
  }
}

// ------------- fused Q/K/V projection GEMM, z-dispatched -------------
// z=0: qin*Wq' + bq, scaled by SCALE_C -> q_ws [B,H,S,D]
// z=1: kin*Wk' + bk                    -> k_ws [B,H,S,D]
// z=2: vin*Wv' + bv                    -> vt_ws [B,H,D,S] (LDS-bounce transpose)
__global__ __launch_bounds__(256, 3) void gemm_qkv(
    const u16* __restrict__ Aq, const u16* __restrict__ Ak, const u16* __restrict__ Av,
    const u16* __restrict__ Bwq, const u16* __restrict__ Bwk, const u16* __restrict__ Bwv,
    const float* __restrict__ bq, const float* __restrict__ bk, const float* __restrict__ bv,
    u16* __restrict__ oq, u16* __restrict__ ok, u16* __restrict__ ov) {
  const int z = blockIdx.z;
  const u16* A = (z == 0) ? Aq : (z == 1) ? Ak : Av;
  const u16* Bt = (z == 0) ? Bwq : (z == 1) ? Bwk : Bwv;
  const float* bias = (z == 0) ? bq : (z == 1) ? bk : bv;
  u16* outb = (z == 0) ? oq : (z == 1) ? ok : ov;
  const int K = (z == 0) ? 1024 : 768;
  const float scale = (z == 0) ? SCALE_C : 1.0f;
  __shared__ __align__(16) u16 smem[18432];
  u16* lA = smem;
  u16* lB = smem + 128 * 64;
  const int tid = threadIdx.x;
  const int bm = blockIdx.x * 128;
  const int bn = blockIdx.y * 128;
  const int wid = tid >> 6, lane = tid & 63;
  const int wm = (wid >> 1) * 64, wn = (wid & 1) * 64;
  const int lrow = lane & 15, quad = lane >> 4;
  const int wrow = lane >> 3, wchk = lane & 7;
  const int sw = lrow & 7;
  f32x4 acc[4][4] = {};
  for (int k0 = 0; k0 < K; k0 += 64) {
    const u16* gA = A + (size_t)(bm + wid * 32) * K + k0;
    const u16* gB = Bt + (size_t)(bn + wid * 32) * K + k0;
#pragma unroll
    for (int c = 0; c < 4; c++) {
      gll16(gA + (size_t)(c * 8 + wrow) * K + (wchk ^ wrow) * 8, &lA[(wid * 32 + c * 8) * 64]);
      gll16(gB + (size_t)(c * 8 + wrow) * K + (wchk ^ wrow) * 8, &lB[(wid * 32 + c * 8) * 64]);
    }
    __syncthreads();
#pragma unroll
    for (int ks = 0; ks < 2; ks++) {
      bf16x8 af[4], bfr[4];
#pragma unroll
      for (int i = 0; i < 4; i++)
        af[i] = *(const bf16x8*)&lA[(wm + i * 16 + lrow) * 64 + ((ks * 4 + quad) ^ sw) * 8];
#pragma unroll
      for (int j = 0; j < 4; j++)
        bfr[j] = *(const bf16x8*)&lB[(wn + j * 16 + lrow) * 64 + ((ks * 4 + quad) ^ sw) * 8];
#pragma unroll
      for (int i = 0; i < 4; i++)
#pragma unroll
        for (int j = 0; j < 4; j++)
          acc[i][j] = __builtin_amdgcn_mfma_f32_16x16x32_bf16(af[i], bfr[j], acc[i][j], 0, 0, 0);
    }
    __syncthreads();
  }
  if (z == 2) {  // V: per-wave 64x64 transpose through LDS, coalesced stores
    u16* tile = smem + wid * (64 * 72);
#pragma unroll
    for (int i = 0; i < 4; i++)
#pragma unroll
      for (int j = 0; j < 4; j++)
#pragma unroll
        for (int r = 0; r < 4; r++) {
          int s_l = i * 16 + quad * 4 + r;
          int d_l = j * 16 + lrow;
          tile[d_l * 72 + s_l] = f2bf(acc[i][j][r] + bias[bn + wn + d_l]);
        }
    __syncthreads();
#pragma unroll
    for (int dd = 0; dd < 8; dd++) {
      int d_l = dd * 8 + (lane >> 3);
      int s_l = (lane & 7) * 8;
      bf16x8 vv = *(const bf16x8*)&tile[d_l * 72 + s_l];
      int row = bm + wm + s_l;
      int col = bn + wn + d_l;
      int b = row >> 11, s = row & 2047;
      int h = col >> 6, d = col & 63;
      *(bf16x8*)&outb[((size_t)(b * 16 + h) * 64 + d) * 2048 + s] = vv;
    }
    return;
  }
#pragma unroll
  for (int i = 0; i < 4; i++)
#pragma unroll
    for (int j = 0; j < 4; j++)
#pragma unroll
      for (int r = 0; r < 4; r++) {
        int row = bm + wm + i * 16 + quad * 4 + r;
        int col = bn + wn + j * 16 + lrow;
        float v = (acc[i][j][r] + bias[col]) * scale;
        int b = row >> 11, s = row & 2047;
        int h = col >> 6, d = col & 63;
        outb[((size_t)(b * 16 + h) * 2048 + s) * 64 + d] = f2bf(v);
      }
}

// ------------- final GEMM: out[M,1024] = ctx*Wo' + bo (fp32 out) -------------
__global__ __launch_bounds__(256, 3) void gemm_out(
    const u16* __restrict__ A, const u16* __restrict__ Bt,
    const float* __restrict__ bias, float* __restrict__ outf) {
  __shared__ __align__(16) u16 smem[16384];
  u16* lA = smem;
  u16* lB = smem + 128 * 64;
  const int tid = threadIdx.x;
  const int bm = blockIdx.x * 128;
  const int bn = blockIdx.y * 128;
  const int wid = tid >> 6, lane = tid & 63;
  const int wm = (wid >> 1) * 64, wn = (wid & 1) * 64;
  const int lrow = lane & 15, quad = lane >> 4;
  const int wrow = lane >> 3, wchk = lane & 7;
  const int sw = lrow & 7;
  f32x4 acc[4][4] = {};
  for (int k0 = 0; k0 < 1024; k0 += 64) {
    const u16* gA = A + (size_t)(bm + wid * 32) * 1024 + k0;
    const u16* gB = Bt + (size_t)(bn + wid * 32) * 1024 + k0;
#pragma unroll
    for (int c = 0; c < 4; c++) {
      gll16(gA + (size_t)(c * 8 + wrow) * 1024 + (wchk ^ wrow) * 8, &lA[(wid * 32 + c * 8) * 64]);
      gll16(gB + (size_t)(c * 8 + wrow) * 1024 + (wchk ^ wrow) * 8, &lB[(wid * 32 + c * 8) * 64]);
    }
    __syncthreads();
#pragma unroll
    for (int ks = 0; ks < 2; ks++) {
      bf16x8 af[4], bfr[4];
#pragma unroll
      for (int i = 0; i < 4; i++)
        af[i] = *(const bf16x8*)&lA[(wm + i * 16 + lrow) * 64 + ((ks * 4 + quad) ^ sw) * 8];
#pragma unroll
      for (int j = 0; j < 4; j++)
        bfr[j] = *(const bf16x8*)&lB[(wn + j * 16 + lrow) * 64 + ((ks * 4 + quad) ^ sw) * 8];
#pragma unroll
      for (int i = 0; i < 4; i++)
#pragma unroll
        for (int j = 0; j < 4; j++)
          acc[i][j] = __builtin_amdgcn_mfma_f32_16x16x32_bf16(af[i], bfr[j], acc[i][j], 0, 0, 0);
    }
    __syncthreads();
  }
#pragma unroll
  for (int i = 0; i < 4; i++)
#pragma unroll
    for (int j = 0; j < 4; j++)
#pragma unroll
      for (int r = 0; r < 4; r++) {
        int row = bm + wm + i * 16 + quad * 4 + r;
        int col = bn + wn + j * 16 + lrow;
        outf[(size_t)row * 1024 + col] = acc[i][j][r] + bias[col];
      }
}

// ---------------- flash attention, kv-split waves, BARRIER-FREE ----------------
// K/V fragments load global->VGPR directly (L2/L3-resident; LDS staging had
// reuse=1 in the kv-split scheme, so it was pure overhead + barrier drains).
// P is wave-private in LDS (in-order DS pipe, lgkmcnt wait only).
// Q was pre-scaled by SCALE_C in the projection -> exp2 directly on scores.
__global__ __launch_bounds__(256, 2) void flash_attn(
    const u16* __restrict__ Q, const u16* __restrict__ Kt,
    const u16* __restrict__ Vt, u16* __restrict__ ctx) {
  __shared__ __align__(16) u16 smem[10752];  // lP 4x2560 | lsums f32[256] @10240
  const int tid = threadIdx.x, wid = tid >> 6, lane = tid & 63;
  u16* lP = smem + wid * 2560;  // [64 q][40 pitch]
  const int bh = blockIdx.x;
  const int q0 = blockIdx.y * 64;
  const int lrow = lane & 15, quad = lane >> 4;
  const size_t base = (size_t)bh * 2048 * 64;
  // Q fragments: 4 q-tiles x 2 ks chunks, in registers for the whole block
  bf16x8 qf[4][2];
#pragma unroll
  for (int qt = 0; qt < 4; qt++)
#pragma unroll
    for (int ks = 0; ks < 2; ks++)
      qf[qt][ks] = *(const bf16x8*)(Q + base + (size_t)(q0 + qt * 16 + lrow) * 64 + ks * 32 + quad * 8);
  f32x4 of[4][4] = {};   // [q-tile][d-tile], kv-partial
  float lsumq[4] = {0.f, 0.f, 0.f, 0.f};
  for (int kv0 = 0; kv0 < 2048; kv0 += 128) {
    const int kvw = kv0 + wid * 32;  // this wave's private kv window
    // direct global loads (was LDS round-trip; same addresses the swizzled
    // staging resolved to — derived from the round-4 read/stage algebra)
    bf16x8 kf[2][2], vf[4];
#pragma unroll
    for (int nt = 0; nt < 2; nt++)
#pragma unroll
      for (int ks = 0; ks < 2; ks++)
        kf[nt][ks] = *(const bf16x8*)(Kt + base + (size_t)(kvw + nt * 16 + lrow) * 64 + ks * 32 + quad * 8);
#pragma unroll
    for (int dt = 0; dt < 4; dt++)
      vf[dt] = *(const bf16x8*)(Vt + base + (size_t)(dt * 16 + lrow) * 2048 + kvw + quad * 8);
    // S^T = K * Q^T for this wave's kv chunk
    f32x4 sfT[2][4];  // [nt (kv 16-tile)][q-tile]
#pragma unroll
    for (int nt = 0; nt < 2; nt++)
#pragma unroll
      for (int qt = 0; qt < 4; qt++) {
        f32x4 s = {};
        s = __builtin_amdgcn_mfma_f32_16x16x32_bf16(kf[nt][0], qf[qt][0], s, 0, 0, 0);
        s = __builtin_amdgcn_mfma_f32_16x16x32_bf16(kf[nt][1], qf[qt][1], s, 0, 0, 0);
        sfT[nt][qt] = s;
      }
    // p = exp2(s) (scale pre-folded); lane's 4 regs = 4 contiguous kv per q-row
#pragma unroll
    for (int nt = 0; nt < 2; nt++)
#pragma unroll
      for (int qt = 0; qt < 4; qt++) {
        float p0 = __builtin_amdgcn_exp2f(sfT[nt][qt][0]);
        float p1 = __builtin_amdgcn_exp2f(sfT[nt][qt][1]);
        float p2 = __builtin_amdgcn_exp2f(sfT[nt][qt][2]);
        float p3 = __builtin_amdgcn_exp2f(sfT[nt][qt][3]);
        lsumq[qt] += (p0 + p1) + (p2 + p3);
        u64 pk = ((u64)pack2bf(p2, p3) << 32) | pack2bf(p0, p1);
        *(u64*)&lP[(qt * 16 + lrow) * 40 + nt * 16 + quad * 4] = pk;
      }
    __asm__ volatile("s_waitcnt lgkmcnt(0)" ::: "memory");  // wave-private P ready
    // O += P(chunk) @ V(chunk)
#pragma unroll
    for (int qt = 0; qt < 4; qt++) {
      bf16x8 pf = *(const bf16x8*)&lP[(qt * 16 + lrow) * 40 + quad * 8];
#pragma unroll
      for (int dt = 0; dt < 4; dt++)
        of[qt][dt] = __builtin_amdgcn_mfma_f32_16x16x32_bf16(pf, vf[dt], of[qt][dt], 0, 0, 0);
    }
  }
  // ---------------- epilogue: cross-wave reduce of lsum and O ----------------
  float lsw[4];
#pragma unroll
  for (int qt = 0; qt < 4; qt++) {
    float v = lsumq[qt];
    v += __shfl_xor(v, 16, 64);
    v += __shfl_xor(v, 32, 64);
    lsw[qt] = v;
  }
  __syncthreads();  // all waves done with lP
  float* lsums = (float*)(smem + 10240);  // [4 waves][64 q]
  if (quad == 0) {
#pragma unroll
    for (int qt = 0; qt < 4; qt++) lsums[wid * 64 + qt * 16 + lrow] = lsw[qt];
  }
  float* rbuf = (float*)smem;  // [64][66] f32 = 16.9 KB, overlays dead lP
  for (int w = 0; w < 4; w++) {
    if (wid == w) {
#pragma unroll
      for (int qt = 0; qt < 4; qt++)
#pragma unroll
        for (int dt = 0; dt < 4; dt++)
#pragma unroll
          for (int r = 0; r < 4; r++) {
            int q = qt * 16 + quad * 4 + r;
            int d = dt * 16 + lrow;
            if (w == 0) rbuf[q * 66 + d] = of[qt][dt][r];
            else        rbuf[q * 66 + d] += of[qt][dt][r];
          }
    }
    __syncthreads();
  }
  const int b = bh >> 4, h = bh & 15;
#pragma unroll
  for (int it = 0; it < 2; it++) {
    int q = wid * 16 + it * 8 + (lane >> 3);
    int d0 = (lane & 7) * 8;
    float inv = 1.f / (lsums[q] + lsums[64 + q] + lsums[128 + q] + lsums[192 + q]);
    u16 o[8];
#pragma unroll
    for (int j = 0; j < 8; j++) o[j] = f2bf(rbuf[q * 66 + d0 + j] * inv);
    *(bf16x8*)&ctx[((size_t)b * 2048 + q0 + q) * 1024 + h * 64 + d0] = *(bf16x8*)o;
  }
}

extern "C" void kernel_launch(void* const* d_in, const int* in_sizes, int n_in,
                              void* d_out, int out_size, void* d_ws, size_t ws_size,
                              hipStream_t stream) {
  const float* query = (const float*)d_in[0];
  const float* key   = (const float*)d_in[1];
  const float* value = (const float*)d_in[2];
  const float* Wq = (const float*)d_in[3];
  const float* bq = (const float*)d_in[4];
  const float* Wk = (const float*)d_in[5];
  const float* bk = (const float*)d_in[6];
  const float* Wv = (const float*)d_in[7];
  const float* bv = (const float*)d_in[8];
  const float* Wo = (const float*)d_in[9];
  const float* bo = (const float*)d_in[10];
  float* out = (float*)d_out;
  char* ws = (char*)d_ws;

  const size_t SZ_QKV = (size_t)8192 * 1024 * 2;
  const size_t SZ_KIN = (size_t)8192 * 768 * 2;
  u16* q_ws  = (u16*)(ws);
  u16* k_ws  = (u16*)(ws + SZ_QKV);
  u16* vt_ws = (u16*)(ws + 2 * SZ_QKV);
  u16* qin   = (u16*)(ws + 3 * SZ_QKV);
  u16* kin   = (u16*)(ws + 4 * SZ_QKV);
  u16* vin   = (u16*)(ws + 4 * SZ_QKV + SZ_KIN);
  u16* ctx   = qin;  // alias: qin dead after Q projection
  u16* wq_t  = (u16*)(ws + 4 * SZ_QKV + 2 * SZ_KIN);
  u16* wk_t  = wq_t + 1024 * 1024;
  u16* wv_t  = wk_t + 1024 * 768;
  u16* wo_t  = wv_t + 1024 * 768;

  conv_bf16<<<8192, 256, 0, stream>>>(query, qin, 8388608);
  conv_bf16<<<6144, 256, 0, stream>>>(key, kin, 6291456);
  conv_bf16<<<6144, 256, 0, stream>>>(value, vin, 6291456);
  transpose_bf16<<<dim3(16, 16), 256, 0, stream>>>(Wq, wq_t, 1024, 1024);
  transpose_bf16<<<dim3(12, 16), 256, 0, stream>>>(Wk, wk_t, 768, 1024);
  transpose_bf16<<<dim3(12, 16), 256, 0, stream>>>(Wv, wv_t, 768, 1024);
  transpose_bf16<<<dim3(16, 16), 256, 0, stream>>>(Wo, wo_t, 1024, 1024);

  gemm_qkv<<<dim3(64, 8, 3), 256, 0, stream>>>(qin, kin, vin, wq_t, wk_t, wv_t,
                                               bq, bk, bv, q_ws, k_ws, vt_ws);

  flash_attn<<<dim3(64, 32), 256, 0, stream>>>(q_ws, k_ws, vt_ws, ctx);

  gemm_out<<<dim3(64, 8), 256, 0, stream>>>(ctx, wo_t, bo, out);
}

// Round 6
// 340.132 us; speedup vs baseline: 1.1369x; 1.1369x over previous
//
#include <hip/hip_runtime.h>

typedef unsigned short u16;
typedef unsigned int u32;
typedef unsigned long long u64;
typedef __attribute__((ext_vector_type(8))) short bf16x8;
typedef __attribute__((ext_vector_type(4))) float f32x4;

__device__ __forceinline__ u16 f2bf(float f) {  // RNE
  union { float f; u32 u; } v; v.f = f;
  u32 r = v.u + 0x7fffu + ((v.u >> 16) & 1u);
  return (u16)(r >> 16);
}
// pack two positive floats to bf16x2 (bias rounding)
__device__ __forceinline__ u32 pack2bf(float a, float b) {
  union { float f; u32 u; } x, y; x.f = a; y.f = b;
  return ((y.u + 0x8000u) & 0xffff0000u) | ((x.u + 0x8000u) >> 16);
}

// async global->LDS, 16B per lane, wave-uniform LDS base + lane*16
__device__ __forceinline__ void gll16(const u16* g, u16* l) {
  __builtin_amdgcn_global_load_lds((__attribute__((address_space(1))) void*)(void*)g,
                                   (__attribute__((address_space(3))) void*)(void*)l,
                                   16, 0, 0);
}

#define SCALE_C 0.18033688011112042f  // (1/sqrt(64)) * log2(e), folded into Q proj

// -------- fp32 -> bf16 convert, all three inputs in ONE launch --------
__global__ void conv_bf16_all(const float* __restrict__ q, const float* __restrict__ k,
                              const float* __restrict__ v, u16* __restrict__ oq,
                              u16* __restrict__ ok, u16* __restrict__ ov) {
  int blk = blockIdx.x;
  const float* in; u16* out; int i;
  if (blk < 8192)       { in = q; out = oq; i = blk * 256 + threadIdx.x; }
  else if (blk < 14336) { in = k; out = ok; i = (blk - 8192) * 256 + threadIdx.x; }
  else                  { in = v; out = ov; i = (blk - 14336) * 256 + threadIdx.x; }
  i *= 4;  // sizes are exact multiples of 1024 per block; no bounds check needed
  float4 vv = *(const float4*)(in + i);
  ushort4 o;
  o.x = f2bf(vv.x); o.y = f2bf(vv.y); o.z = f2bf(vv.z); o.w = f2bf(vv.w);
  *(ushort4*)(out + i) = o;
}

// ------ all 4 weight transposes in ONE launch: W[K,1024] -> T[1024,K] bf16 ------
__global__ void transpose_all(const float* __restrict__ Wq, const float* __restrict__ Wk,
                              const float* __restrict__ Wv, const float* __restrict__ Wo,
                              u16* __restrict__ tq, u16* __restrict__ tk,
                              u16* __restrict__ tv, u16* __restrict__ to_) {
  const int z = blockIdx.z;
  const float* W = (z == 0) ? Wq : (z == 1) ? Wk : (z == 2) ? Wv : Wo;
  u16* T = (z == 0) ? tq : (z == 1) ? tk : (z == 2) ? tv : to_;
  const int K = (z == 0 || z == 3) ? 1024 : 768;
  const int k0 = blockIdx.x * 64;
  if (k0 >= K) return;  // uniform
  __shared__ u16 tile[64 * 72];
  const int n0 = blockIdx.y * 64;
  const int t = threadIdx.x, c = t & 63, rb = t >> 6;
#pragma unroll
  for (int rr = 0; rr < 64; rr += 4) {
    int r = rr + rb;
    tile[r * 72 + c] = f2bf(W[(size_t)(k0 + r) * 1024 + n0 + c]);
  }
  __syncthreads();
#pragma unroll
  for (int rr = 0; rr < 64; rr += 4) {
    int n = rr + rb;
    T[(size_t)(n0 + n) * K + k0 + c] = tile[c * 72 + n];
  }
}

// ------------- fused Q/K/V projection GEMM, z-dispatched -------------
// z=0: qin*Wq' + bq, scaled by SCALE_C -> q_ws [B,H,S,D]
// z=1: kin*Wk' + bk                    -> k_ws [B,H,S,D]
// z=2: vin*Wv' + bv                    -> vt_ws [B,H,D,S] (LDS-bounce transpose)
// All epilogues go through a per-wave LDS bounce -> bf16x8 vector stores.
__global__ __launch_bounds__(256, 3) void gemm_qkv(
    const u16* __restrict__ Aq, const u16* __restrict__ Ak, const u16* __restrict__ Av,
    const u16* __restrict__ Bwq, const u16* __restrict__ Bwk, const u16* __restrict__ Bwv,
    const float* __restrict__ bq, const float* __restrict__ bk, const float* __restrict__ bv,
    u16* __restrict__ oq, u16* __restrict__ ok, u16* __restrict__ ov) {
  const int z = blockIdx.z;
  const u16* A = (z == 0) ? Aq : (z == 1) ? Ak : Av;
  const u16* Bt = (z == 0) ? Bwq : (z == 1) ? Bwk : Bwv;
  const float* bias = (z == 0) ? bq : (z == 1) ? bk : bv;
  u16* outb = (z == 0) ? oq : (z == 1) ? ok : ov;
  const int K = (z == 0) ? 1024 : 768;
  const float scale = (z == 0) ? SCALE_C : 1.0f;
  __shared__ __align__(16) u16 smem[18432];
  u16* lA = smem;
  u16* lB = smem + 128 * 64;
  const int tid = threadIdx.x;
  const int bm = blockIdx.x * 128;
  const int bn = blockIdx.y * 128;
  const int wid = tid >> 6, lane = tid & 63;
  const int wm = (wid >> 1) * 64, wn = (wid & 1) * 64;
  const int lrow = lane & 15, quad = lane >> 4;
  const int wrow = lane >> 3, wchk = lane & 7;
  const int sw = lrow & 7;
  f32x4 acc[4][4] = {};
  for (int k0 = 0; k0 < K; k0 += 64) {
    const u16* gA = A + (size_t)(bm + wid * 32) * K + k0;
    const u16* gB = Bt + (size_t)(bn + wid * 32) * K + k0;
#pragma unroll
    for (int c = 0; c < 4; c++) {
      gll16(gA + (size_t)(c * 8 + wrow) * K + (wchk ^ wrow) * 8, &lA[(wid * 32 + c * 8) * 64]);
      gll16(gB + (size_t)(c * 8 + wrow) * K + (wchk ^ wrow) * 8, &lB[(wid * 32 + c * 8) * 64]);
    }
    __syncthreads();
#pragma unroll
    for (int ks = 0; ks < 2; ks++) {
      bf16x8 af[4], bfr[4];
#pragma unroll
      for (int i = 0; i < 4; i++)
        af[i] = *(const bf16x8*)&lA[(wm + i * 16 + lrow) * 64 + ((ks * 4 + quad) ^ sw) * 8];
#pragma unroll
      for (int j = 0; j < 4; j++)
        bfr[j] = *(const bf16x8*)&lB[(wn + j * 16 + lrow) * 64 + ((ks * 4 + quad) ^ sw) * 8];
#pragma unroll
      for (int i = 0; i < 4; i++)
#pragma unroll
        for (int j = 0; j < 4; j++)
          acc[i][j] = __builtin_amdgcn_mfma_f32_16x16x32_bf16(af[i], bfr[j], acc[i][j], 0, 0, 0);
    }
    __syncthreads();
  }
  // per-wave LDS bounce tile (overlays lA/lB; safe after final barrier)
  u16* tile = smem + wid * (64 * 72);
  if (z == 2) {  // V: transpose to [d][s], coalesced stores along s
#pragma unroll
    for (int i = 0; i < 4; i++)
#pragma unroll
      for (int j = 0; j < 4; j++)
#pragma unroll
        for (int r = 0; r < 4; r++) {
          int s_l = i * 16 + quad * 4 + r;
          int d_l = j * 16 + lrow;
          tile[d_l * 72 + s_l] = f2bf(acc[i][j][r] + bias[bn + wn + d_l]);
        }
    __syncthreads();
#pragma unroll
    for (int dd = 0; dd < 8; dd++) {
      int d_l = dd * 8 + (lane >> 3);
      int s_l = (lane & 7) * 8;
      bf16x8 vv = *(const bf16x8*)&tile[d_l * 72 + s_l];
      int row = bm + wm + s_l;
      int col = bn + wn + d_l;
      int b = row >> 11, s = row & 2047;
      int h = col >> 6, d = col & 63;
      *(bf16x8*)&outb[((size_t)(b * 16 + h) * 64 + d) * 2048 + s] = vv;
    }
    return;
  }
  // Q/K: same orientation bounce -> vector stores along d (was 64 scalar b16)
#pragma unroll
  for (int i = 0; i < 4; i++)
#pragma unroll
    for (int j = 0; j < 4; j++)
#pragma unroll
      for (int r = 0; r < 4; r++) {
        int s_l = i * 16 + quad * 4 + r;
        int d_l = j * 16 + lrow;
        tile[s_l * 72 + d_l] = f2bf((acc[i][j][r] + bias[bn + wn + d_l]) * scale);
      }
  __syncthreads();
#pragma unroll
  for (int it = 0; it < 8; it++) {
    int s_l = it * 8 + (lane >> 3);
    int d0 = (lane & 7) * 8;
    bf16x8 vv = *(const bf16x8*)&tile[s_l * 72 + d0];
    int row = bm + wm + s_l;
    int col = bn + wn + d0;
    int b = row >> 11, s = row & 2047;
    int h = col >> 6, d = col & 63;
    *(bf16x8*)&outb[((size_t)(b * 16 + h) * 2048 + s) * 64 + d] = vv;
  }
}

// ------------- final GEMM: out[M,1024] = ctx*Wo' + bo (fp32 out) -------------
__global__ __launch_bounds__(256, 3) void gemm_out(
    const u16* __restrict__ A, const u16* __restrict__ Bt,
    const float* __restrict__ bias, float* __restrict__ outf) {
  __shared__ __align__(16) u16 smem[16384];
  u16* lA = smem;
  u16* lB = smem + 128 * 64;
  const int tid = threadIdx.x;
  const int bm = blockIdx.x * 128;
  const int bn = blockIdx.y * 128;
  const int wid = tid >> 6, lane = tid & 63;
  const int wm = (wid >> 1) * 64, wn = (wid & 1) * 64;
  const int lrow = lane & 15, quad = lane >> 4;
  const int wrow = lane >> 3, wchk = lane & 7;
  const int sw = lrow & 7;
  f32x4 acc[4][4] = {};
  for (int k0 = 0; k0 < 1024; k0 += 64) {
    const u16* gA = A + (size_t)(bm + wid * 32) * 1024 + k0;
    const u16* gB = Bt + (size_t)(bn + wid * 32) * 1024 + k0;
#pragma unroll
    for (int c = 0; c < 4; c++) {
      gll16(gA + (size_t)(c * 8 + wrow) * 1024 + (wchk ^ wrow) * 8, &lA[(wid * 32 + c * 8) * 64]);
      gll16(gB + (size_t)(c * 8 + wrow) * 1024 + (wchk ^ wrow) * 8, &lB[(wid * 32 + c * 8) * 64]);
    }
    __syncthreads();
#pragma unroll
    for (int ks = 0; ks < 2; ks++) {
      bf16x8 af[4], bfr[4];
#pragma unroll
      for (int i = 0; i < 4; i++)
        af[i] = *(const bf16x8*)&lA[(wm + i * 16 + lrow) * 64 + ((ks * 4 + quad) ^ sw) * 8];
#pragma unroll
      for (int j = 0; j < 4; j++)
        bfr[j] = *(const bf16x8*)&lB[(wn + j * 16 + lrow) * 64 + ((ks * 4 + quad) ^ sw) * 8];
#pragma unroll
      for (int i = 0; i < 4; i++)
#pragma unroll
        for (int j = 0; j < 4; j++)
          acc[i][j] = __builtin_amdgcn_mfma_f32_16x16x32_bf16(af[i], bfr[j], acc[i][j], 0, 0, 0);
    }
    __syncthreads();
  }
#pragma unroll
  for (int i = 0; i < 4; i++)
#pragma unroll
    for (int j = 0; j < 4; j++)
#pragma unroll
      for (int r = 0; r < 4; r++) {
        int row = bm + wm + i * 16 + quad * 4 + r;
        int col = bn + wn + j * 16 + lrow;
        outf[(size_t)row * 1024 + col] = acc[i][j][r] + bias[col];
      }
}

// ---------------- flash attention: kv-split, barrier-free K-loop ----------------
// K staging is wave-private (writer == reader) -> double-buffered per-wave LDS
// with gll prefetch one full iter ahead, drained by explicit vmcnt(8) that
// leaves {V loads, new gll} in flight. V goes global->VGPR (L2-resident),
// issued BEFORE the glls so the PV V-wait never drains the prefetch.
// P wave-private in LDS (in-order DS + lgkmcnt only). ZERO barriers in loop.
__global__ __launch_bounds__(256, 3) void flash_attn(
    const u16* __restrict__ Q, const u16* __restrict__ Kt,
    const u16* __restrict__ Vt, u16* __restrict__ ctx) {
  __shared__ __align__(16) u16 smem[26624];  // lK dbuf 2x16KB | lP 4x5KB
  const int tid = threadIdx.x, wid = tid >> 6, lane = tid & 63;
  u16* lP = smem + 16384 + wid * 2560;       // [64 q][40 pitch]
  const int bh = blockIdx.x;
  const int q0 = blockIdx.y * 64;
  const int lrow = lane & 15, quad = lane >> 4;
  const size_t base = (size_t)bh * 2048 * 64;
  const int wrow8 = lane >> 3, wchk8 = lane & 7;
  // Q fragments: 4 q-tiles x 2 ks chunks, in registers for the whole block
  bf16x8 qf[4][2];
#pragma unroll
  for (int qt = 0; qt < 4; qt++)
#pragma unroll
    for (int ks = 0; ks < 2; ks++)
      qf[qt][ks] = *(const bf16x8*)(Q + base + (size_t)(q0 + qt * 16 + lrow) * 64 + ks * 32 + quad * 8);
  f32x4 of[4][4] = {};   // [q-tile][d-tile], kv-partial
  float lsumq[4] = {0.f, 0.f, 0.f, 0.f};
  // prologue: stage K window 0 (this wave's 32 kv rows) into buf 0
  {
    const u16* gK = Kt + base + (size_t)(wid * 32) * 64;
    u16* dst = smem + wid * 2048;
#pragma unroll
    for (int c = 0; c < 4; c++)
      gll16(gK + (size_t)(c * 8 + wrow8) * 64 + (wchk8 ^ wrow8) * 8, dst + c * 8 * 64);
  }
  for (int it = 0; it < 16; ++it) {
    const int kvw = it * 128 + wid * 32;  // this wave's kv window
    const u16* lKw = smem + (it & 1) * 8192 + wid * 2048;
    // V fragments for THIS iter: global->VGPR, issued first (oldest)
    bf16x8 vf[4];
#pragma unroll
    for (int dt = 0; dt < 4; dt++)
      vf[dt] = *(const bf16x8*)(Vt + base + (size_t)(dt * 16 + lrow) * 2048 + kvw + quad * 8);
    __asm__ volatile("" ::: "memory");  // pin: V loads precede the K prefetch
    if (it < 15) {
      // prefetch NEXT K window into the other buffer
      const u16* gK = Kt + base + (size_t)(kvw + 128) * 64;
      u16* dst = smem + ((it + 1) & 1) * 8192 + wid * 2048;
#pragma unroll
      for (int c = 0; c < 4; c++)
        gll16(gK + (size_t)(c * 8 + wrow8) * 64 + (wchk8 ^ wrow8) * 8, dst + c * 8 * 64);
      // drain everything older than {V x4, gll x4} -> current lK buffer ready
      __asm__ volatile("s_waitcnt vmcnt(8)" ::: "memory");
    } else {
      __asm__ volatile("s_waitcnt vmcnt(4)" ::: "memory");  // keep only V x4
    }
    // S^T = K * Q^T for this wave's kv chunk
    f32x4 sfT[2][4];
#pragma unroll
    for (int nt = 0; nt < 2; nt++) {
      bf16x8 kf0 = *(const bf16x8*)&lKw[(nt * 16 + lrow) * 64 + (quad ^ (lrow & 7)) * 8];
      bf16x8 kf1 = *(const bf16x8*)&lKw[(nt * 16 + lrow) * 64 + ((4 + quad) ^ (lrow & 7)) * 8];
#pragma unroll
      for (int qt = 0; qt < 4; qt++) {
        f32x4 s = {};
        s = __builtin_amdgcn_mfma_f32_16x16x32_bf16(kf0, qf[qt][0], s, 0, 0, 0);
        s = __builtin_amdgcn_mfma_f32_16x16x32_bf16(kf1, qf[qt][1], s, 0, 0, 0);
        sfT[nt][qt] = s;
      }
    }
    // p = exp2(s) (scale pre-folded); lane's 4 regs = 4 contiguous kv per q-row
#pragma unroll
    for (int nt = 0; nt < 2; nt++)
#pragma unroll
      for (int qt = 0; qt < 4; qt++) {
        float p0 = __builtin_amdgcn_exp2f(sfT[nt][qt][0]);
        float p1 = __builtin_amdgcn_exp2f(sfT[nt][qt][1]);
        float p2 = __builtin_amdgcn_exp2f(sfT[nt][qt][2]);
        float p3 = __builtin_amdgcn_exp2f(sfT[nt][qt][3]);
        lsumq[qt] += (p0 + p1) + (p2 + p3);
        u64 pk = ((u64)pack2bf(p2, p3) << 32) | pack2bf(p0, p1);
        *(u64*)&lP[(qt * 16 + lrow) * 40 + nt * 16 + quad * 4] = pk;
      }
    __asm__ volatile("s_waitcnt lgkmcnt(0)" ::: "memory");  // wave-private P ready
    // O += P(chunk) @ V(chunk)
#pragma unroll
    for (int qt = 0; qt < 4; qt++) {
      bf16x8 pf = *(const bf16x8*)&lP[(qt * 16 + lrow) * 40 + quad * 8];
#pragma unroll
      for (int dt = 0; dt < 4; dt++)
        of[qt][dt] = __builtin_amdgcn_mfma_f32_16x16x32_bf16(pf, vf[dt], of[qt][dt], 0, 0, 0);
    }
  }
  // ---------------- epilogue: cross-wave reduce of lsum and O ----------------
  float lsw[4];
#pragma unroll
  for (int qt = 0; qt < 4; qt++) {
    float v = lsumq[qt];
    v += __shfl_xor(v, 16, 64);
    v += __shfl_xor(v, 32, 64);
    lsw[qt] = v;
  }
  __syncthreads();  // all waves done with lP / lK
  float* lsums = (float*)(smem + 16384);  // overlays dead lP: [4 waves][64 q]
  if (quad == 0) {
#pragma unroll
    for (int qt = 0; qt < 4; qt++) lsums[wid * 64 + qt * 16 + lrow] = lsw[qt];
  }
  float* rbuf = (float*)smem;  // [64][66] f32 = 16.9 KB, overlays dead lK
  for (int w = 0; w < 4; w++) {
    if (wid == w) {
#pragma unroll
      for (int qt = 0; qt < 4; qt++)
#pragma unroll
        for (int dt = 0; dt < 4; dt++)
#pragma unroll
          for (int r = 0; r < 4; r++) {
            int q = qt * 16 + quad * 4 + r;
            int d = dt * 16 + lrow;
            if (w == 0) rbuf[q * 66 + d] = of[qt][dt][r];
            else        rbuf[q * 66 + d] += of[qt][dt][r];
          }
    }
    __syncthreads();
  }
  const int b = bh >> 4, h = bh & 15;
#pragma unroll
  for (int it = 0; it < 2; it++) {
    int q = wid * 16 + it * 8 + (lane >> 3);
    int d0 = (lane & 7) * 8;
    float inv = 1.f / (lsums[q] + lsums[64 + q] + lsums[128 + q] + lsums[192 + q]);
    u16 o[8];
#pragma unroll
    for (int j = 0; j < 8; j++) o[j] = f2bf(rbuf[q * 66 + d0 + j] * inv);
    *(bf16x8*)&ctx[((size_t)b * 2048 + q0 + q) * 1024 + h * 64 + d0] = *(bf16x8*)o;
  }
}

extern "C" void kernel_launch(void* const* d_in, const int* in_sizes, int n_in,
                              void* d_out, int out_size, void* d_ws, size_t ws_size,
                              hipStream_t stream) {
  const float* query = (const float*)d_in[0];
  const float* key   = (const float*)d_in[1];
  const float* value = (const float*)d_in[2];
  const float* Wq = (const float*)d_in[3];
  const float* bq = (const float*)d_in[4];
  const float* Wk = (const float*)d_in[5];
  const float* bk = (const float*)d_in[6];
  const float* Wv = (const float*)d_in[7];
  const float* bv = (const float*)d_in[8];
  const float* Wo = (const float*)d_in[9];
  const float* bo = (const float*)d_in[10];
  float* out = (float*)d_out;
  char* ws = (char*)d_ws;

  const size_t SZ_QKV = (size_t)8192 * 1024 * 2;
  const size_t SZ_KIN = (size_t)8192 * 768 * 2;
  u16* q_ws  = (u16*)(ws);
  u16* k_ws  = (u16*)(ws + SZ_QKV);
  u16* vt_ws = (u16*)(ws + 2 * SZ_QKV);
  u16* qin   = (u16*)(ws + 3 * SZ_QKV);
  u16* kin   = (u16*)(ws + 4 * SZ_QKV);
  u16* vin   = (u16*)(ws + 4 * SZ_QKV + SZ_KIN);
  u16* ctx   = qin;  // alias: qin dead after Q projection
  u16* wq_t  = (u16*)(ws + 4 * SZ_QKV + 2 * SZ_KIN);
  u16* wk_t  = wq_t + 1024 * 1024;
  u16* wv_t  = wk_t + 1024 * 768;
  u16* wo_t  = wv_t + 1024 * 768;

  conv_bf16_all<<<20480, 256, 0, stream>>>(query, key, value, qin, kin, vin);
  transpose_all<<<dim3(16, 16, 4), 256, 0, stream>>>(Wq, Wk, Wv, Wo,
                                                     wq_t, wk_t, wv_t, wo_t);
  gemm_qkv<<<dim3(64, 8, 3), 256, 0, stream>>>(qin, kin, vin, wq_t, wk_t, wv_t,
                                               bq, bk, bv, q_ws, k_ws, vt_ws);
  flash_attn<<<dim3(64, 32), 256, 0, stream>>>(q_ws, k_ws, vt_ws, ctx);
  gemm_out<<<dim3(64, 8), 256, 0, stream>>>(ctx, wo_t, bo, out);
}